// Round 4
// baseline (579.890 us; speedup 1.0000x reference)
//
#include <hip/hip_runtime.h>
#include <hip/hip_bf16.h>
#include <math.h>

typedef short bf16x8 __attribute__((ext_vector_type(8)));
typedef float f32x4 __attribute__((ext_vector_type(4)));
typedef unsigned short u16;

#define N_TOK  4096
#define D_IN   512
#define D_ATTN 64
#define NB2    2048
#define CAPW   128
#define TOPP   0.9f
#define LN_EPS 1e-5f
#define AMAXV  (N_TOK - 1)

__device__ __forceinline__ u16 f2bf(float f) {
  unsigned int u = __float_as_uint(f);
  return (u16)((u + 0x7FFFu + ((u >> 16) & 1u)) >> 16);
}

__device__ __forceinline__ void gload16(const u16* g, u16* l) {
  __builtin_amdgcn_global_load_lds(
      (const __attribute__((address_space(1))) unsigned int*)g,
      (__attribute__((address_space(3))) unsigned int*)l, 16, 0, 0);
}

__device__ __forceinline__ int bkt(float e, float emin, float scale) {
  int b = (int)((e - emin) * scale);
  return (b < 0) ? 0 : ((b > NB2 - 1) ? NB2 - 1 : b);
}

// ---------------------------------------------------------------------------
// gemm128 (unchanged from round 3): C = sum_seg rowmap(A_s) @ B_s^T.
// ---------------------------------------------------------------------------
template<int EPI, int NSEG, int KSEG>
__global__ __launch_bounds__(256)
void gemm128(const u16* __restrict__ A0, int lda0, int sh0, const u16* __restrict__ B0, int ldb0,
             const u16* __restrict__ A1, int lda1, int sh1, const u16* __restrict__ B1, int ldb1,
             const u16* __restrict__ A2, int lda2, int sh2, const u16* __restrict__ B2, int ldb2,
             float* __restrict__ Cf, u16* __restrict__ Cb, u16* __restrict__ CbT,
             int ldc, int ldct)
{
  __shared__ u16 sA[2][128 * 64];
  __shared__ u16 sB[2][64 * 64];

  const int tid  = threadIdx.x;
  const int wave = tid >> 6;
  const int lane = tid & 63;
  const int l15  = lane & 15;
  const int l4   = lane >> 4;
  const int brow = blockIdx.y << 7;
  const int bcol = blockIdx.x << 6;
  const int wr64 = (wave >> 1) << 6;
  const int wc32 = (wave & 1) << 5;

  constexpr int IPSEG = KSEG >> 6;
  constexpr int TOTAL = NSEG * IPSEG;

  auto stage = [&](int buf, int it) {
    int seg = (NSEG == 1) ? 0 : (it / IPSEG);
    int kk  = (NSEG == 1) ? (it << 6) : ((it % IPSEG) << 6);
    const u16 *Ab, *Bb; int la, lb, sh;
    if (seg == 0)      { Ab = A0; la = lda0; sh = sh0; Bb = B0; lb = ldb0; }
    else if (seg == 1) { Ab = A1; la = lda1; sh = sh1; Bb = B1; lb = ldb1; }
    else               { Ab = A2; la = lda2; sh = sh2; Bb = B2; lb = ldb2; }
#pragma unroll
    for (int q = 0; q < 4; ++q) {
      int idx = q * 256 + tid;
      int row = idx >> 3;
      int chunk = (idx & 7) ^ (row & 7);
      int r = brow + row + sh;
      r = (r < 0) ? 0 : ((r > AMAXV) ? AMAXV : r);
      gload16(Ab + (size_t)r * la + kk + chunk * 8, &sA[buf][idx * 8]);
    }
#pragma unroll
    for (int q = 0; q < 2; ++q) {
      int idx = q * 256 + tid;
      int row = idx >> 3;
      int chunk = (idx & 7) ^ (row & 7);
      gload16(Bb + (size_t)(bcol + row) * lb + kk + chunk * 8, &sB[buf][idx * 8]);
    }
  };

  f32x4 acc[4][2];
#pragma unroll
  for (int m = 0; m < 4; ++m)
#pragma unroll
    for (int n = 0; n < 2; ++n) {
      acc[m][n][0] = 0.f; acc[m][n][1] = 0.f; acc[m][n][2] = 0.f; acc[m][n][3] = 0.f;
    }

  stage(0, 0);
  asm volatile("s_waitcnt vmcnt(0)" ::: "memory");
  __builtin_amdgcn_s_barrier();

  for (int i = 0; i < TOTAL; ++i) {
    const int c = i & 1;
    if (i + 1 < TOTAL) stage(c ^ 1, i + 1);
#pragma unroll
    for (int ks = 0; ks < 2; ++ks) {
      bf16x8 af[4], bfr[2];
#pragma unroll
      for (int m = 0; m < 4; ++m) {
        int ar = wr64 + m * 16 + l15;
        af[m] = *(const bf16x8*)&sA[c][ar * 64 + (((ks << 2) + l4) ^ (ar & 7)) * 8];
      }
#pragma unroll
      for (int n = 0; n < 2; ++n) {
        int br = wc32 + n * 16 + l15;
        bfr[n] = *(const bf16x8*)&sB[c][br * 64 + (((ks << 2) + l4) ^ (br & 7)) * 8];
      }
#pragma unroll
      for (int m = 0; m < 4; ++m)
#pragma unroll
        for (int n = 0; n < 2; ++n)
          acc[m][n] = __builtin_amdgcn_mfma_f32_16x16x32_bf16(af[m], bfr[n], acc[m][n], 0, 0, 0);
    }
    asm volatile("s_waitcnt vmcnt(0)" ::: "memory");
    __builtin_amdgcn_s_barrier();
  }

#pragma unroll
  for (int m = 0; m < 4; ++m)
#pragma unroll
    for (int n = 0; n < 2; ++n)
#pragma unroll
      for (int r = 0; r < 4; ++r) {
        const int row = brow + wr64 + m * 16 + l4 * 4 + r;
        const int col = bcol + wc32 + n * 16 + l15;
        const float v = acc[m][n][r];
        if (EPI == 0) Cf[(size_t)row * ldc + col] = v;
        if (EPI == 1) Cb[(size_t)row * ldc + col] = f2bf(tanhf(v));
        if (EPI == 2) Cb[(size_t)row * ldc + col] = f2bf(v);
        if (EPI == 3) Cf[(size_t)row * ldc + col] += v;
        if (EPI == 4) {
          u16 hv = f2bf(v);
          Cb [(size_t)row * ldc  + col] = hv;
          CbT[(size_t)col * ldct + row] = hv;
        }
      }
}

// ---------------------------------------------------------------------------
// Wave-synchronous nucleus: one row per WAVE, zero barriers.
// Row (64 f32/lane) in registers; per-wave private 2048-bucket LDS histogram
// with lane-rotated chunk layout (conflict-free zero/read, static reg idx).
// Suffix scan + E via shuffles. Boundary refine via small per-wave LDS list.
// Output bf16 A row written in-place over the f32 scores row.
// ---------------------------------------------------------------------------
__global__ __launch_bounds__(256)
void nucleus_wave(float* __restrict__ S)
{
  const int wid = threadIdx.x >> 6;
  const int l   = threadIdx.x & 63;
  const int row = (blockIdx.x << 2) + wid;
  float* srow = S + (size_t)row * N_TOK;
  u16*   arow = (u16*)srow;

  __shared__ float hist[4][NB2];            // 32 KB
  __shared__ float ge[4][CAPW];             // 2 KB
  __shared__ int   gcol[4][CAPW];           // 2 KB
  __shared__ unsigned char kf[4][CAPW];     // 0.5 KB
  __shared__ int   cnts[4];

  float* H = hist[wid];

  // ---- load row (vectorized) + wave max/min
  float evf[64];
  float lmax = -3.402823466e38f, lmin = 3.402823466e38f;
#pragma unroll
  for (int q = 0; q < 16; ++q) {
    float4 v = ((const float4*)srow)[(q << 6) + l];
    evf[4*q+0] = v.x; evf[4*q+1] = v.y; evf[4*q+2] = v.z; evf[4*q+3] = v.w;
    lmax = fmaxf(lmax, fmaxf(fmaxf(v.x, v.y), fmaxf(v.z, v.w)));
    lmin = fminf(lmin, fminf(fminf(v.x, v.y), fminf(v.z, v.w)));
  }
#pragma unroll
  for (int o = 32; o; o >>= 1) {
    lmax = fmaxf(lmax, __shfl_xor(lmax, o));
    lmin = fminf(lmin, __shfl_xor(lmin, o));
  }
  const float smax  = lmax;
  const float emin  = __expf(lmin - smax);
  const float scale = (float)NB2 / fmaxf(1.0f - emin, 1e-30f);

  // ---- zero my histogram (lane-rotated slots; in-wave DS ordering)
  if (l == 0) cnts[wid] = 0;
  float4 z4; z4.x = 0.f; z4.y = 0.f; z4.z = 0.f; z4.w = 0.f;
#pragma unroll
  for (int pc = 0; pc < 8; ++pc)
    ((float4*)(H + (l << 5)))[(pc + l) & 7] = z4;

  // ---- exp (in regs) + exp-mass histogram via LDS atomics
#pragma unroll
  for (int qc = 0; qc < 64; ++qc) {
    float e = __expf(evf[qc] - smax);
    evf[qc] = e;
    int b  = bkt(e, emin, scale);
    int ol = b >> 5;
    int jc = (b >> 2) & 7;
    atomicAdd(&H[(ol << 5) + (((jc + ol) & 7) << 2) + (b & 3)], e);
  }

  // ---- per-lane chunk read (rotated -> conflict-free, static reg index)
  float4 h4[8];
#pragma unroll
  for (int jc = 0; jc < 8; ++jc)
    h4[jc] = ((const float4*)(H + (l << 5)))[(jc + l) & 7];
  float sl = 0.f;
#pragma unroll
  for (int jc = 0; jc < 8; ++jc)
    sl += (h4[jc].x + h4[jc].y) + (h4[jc].z + h4[jc].w);

  // ---- suffix scan across lanes (lane l owns buckets [32l,32l+32))
  float v = sl;
#pragma unroll
  for (int o = 1; o < 64; o <<= 1) {
    float t = __shfl_down(v, o);
    if (l + o < 64) v += t;
  }
  const float E = __shfl(v, 0);
  const float above = v - sl;
  const float T = TOPP * E;

  // ---- boundary walk over my 32 buckets, descending (registers only)
  float Arun = above;
  int   lb = -1;
  float Ab = 0.f;
#pragma unroll
  for (int j = 31; j >= 0; --j) {
    float bm;
    switch (j & 3) {
      case 0: bm = h4[j >> 2].x; break;
      case 1: bm = h4[j >> 2].y; break;
      case 2: bm = h4[j >> 2].z; break;
      default: bm = h4[j >> 2].w; break;
    }
    if (Arun < T && Arun + bm >= T) { lb = j; Ab = Arun; }
    Arun += bm;
  }
  int bst_l = (lb >= 0) ? ((l << 5) | lb) : -1;
  int bstar = bst_l;
#pragma unroll
  for (int o = 32; o; o >>= 1) bstar = max(bstar, __shfl_xor(bstar, o));
  float Ab_l = (bst_l == bstar && bstar >= 0) ? Ab : 0.f;
#pragma unroll
  for (int o = 32; o; o >>= 1) Ab_l += __shfl_xor(Ab_l, o);
  const float Abnd = Ab_l;

  // ---- gather boundary-bucket elements into per-wave list
  if (bstar >= 0) {
#pragma unroll
    for (int qc = 0; qc < 64; ++qc) {
      float e = evf[qc];
      if (bkt(e, emin, scale) == bstar) {
        int i = atomicAdd(&cnts[wid], 1);
        if (i < CAPW) {
          ge[wid][i] = e;
          gcol[wid][i] = ((qc >> 2) << 8) + (l << 2) + (qc & 3);
        }
      }
    }
  }
  int cnt = cnts[wid];               // in-wave DS order: after my atomics
  const bool fb = (cnt > CAPW);

  // ---- refine boundary (exact tie-aware prefix), accumulate kept mass
  float keptb = 0.f;
  if (bstar >= 0) {
    if (!fb) {
      for (int i = l; i < cnt; i += 64) {
        float ei = ge[wid][i]; int ci = gcol[wid][i];
        float m = Abnd;
        for (int t = 0; t < cnt; ++t) {
          float el = ge[wid][t];
          if (el > ei || (el == ei && gcol[wid][t] < ci)) m += el;
        }
        unsigned char kp = (m < T) ? 1 : 0;
        kf[wid][i] = kp;
        if (kp) keptb += ei;
      }
    } else {
      // pathological fallback: exact scan from global (srow still intact)
#pragma unroll
      for (int qc = 0; qc < 64; ++qc) {
        float ej = evf[qc];
        if (bkt(ej, emin, scale) != bstar) continue;
        int cj = ((qc >> 2) << 8) + (l << 2) + (qc & 3);
        float m = Abnd;
        for (int t = 0; t < N_TOK; ++t) {
          float el = __expf(srow[t] - smax);
          if (bkt(el, emin, scale) == bstar &&
              (el > ej || (el == ej && t < cj))) m += el;
        }
        if (m < T) keptb += ej;
      }
    }
  }
#pragma unroll
  for (int o = 32; o; o >>= 1) keptb += __shfl_xor(keptb, o);

  const float den  = (bstar >= 0) ? (Abnd + keptb) : E;
  const float invd = 1.0f / den;

  // ---- write A row as bf16, in place
#pragma unroll
  for (int q = 0; q < 16; ++q) {
    u16 rr[4];
#pragma unroll
    for (int c = 0; c < 4; ++c) {
      float e = evf[4*q + c];
      int b = bkt(e, emin, scale);
      float val = 0.f;
      if (b > bstar) {
        val = e * invd;
      } else if (b == bstar) {
        bool kp = false;
        int col = (q << 8) + (l << 2) + c;
        if (!fb) {
          for (int t = 0; t < cnt; ++t)
            if (gcol[wid][t] == col) { kp = (kf[wid][t] != 0); break; }
        } else {
          float m = Abnd;
          for (int t = 0; t < N_TOK; ++t) {
            float el = __expf(srow[t] - smax);
            if (bkt(el, emin, scale) == bstar &&
                (el > e || (el == e && t < col))) m += el;
          }
          kp = (m < T);
        }
        if (kp) val = e * invd;
      }
      rr[c] = f2bf(val);
    }
    ushort4 o4 = make_ushort4(rr[0], rr[1], rr[2], rr[3]);
    ((ushort4*)arow)[(q << 6) + l] = o4;
  }
}

// ---------------------------------------------------------------------------
__global__ void cvt_bf4(const float* __restrict__ src, u16* __restrict__ d1,
                        u16* __restrict__ d2, int n4)
{
  int i = blockIdx.x * 256 + threadIdx.x;
  if (i < n4) {
    float4 v = ((const float4*)src)[i];
    ushort4 o;
    o.x = f2bf(v.x); o.y = f2bf(v.y); o.z = f2bf(v.z); o.w = f2bf(v.w);
    ((ushort4*)d1)[i] = o;
    if (d2) ((ushort4*)d2)[i] = o;
  }
}

__global__ __launch_bounds__(256)
void tpose_bf(const float* __restrict__ X, u16* __restrict__ XT)
{
  __shared__ u16 tile[32][33];
  const int bc = blockIdx.x * 32;
  const int br = blockIdx.y * 32;
  const int tx = threadIdx.x & 31, ty = threadIdx.x >> 5;
#pragma unroll
  for (int i = 0; i < 32; i += 8)
    tile[ty + i][tx] = f2bf(X[(size_t)(br + ty + i) * D_IN + bc + tx]);
  __syncthreads();
#pragma unroll
  for (int i = 0; i < 32; i += 8)
    XT[(size_t)(bc + ty + i) * N_TOK + br + tx] = tile[tx][ty + i];
}

__global__ __launch_bounds__(256)
void ln_kernel(const float* __restrict__ X, float* Z,
               const float* __restrict__ gamma, const float* __restrict__ beta)
{
  const int row = blockIdx.x, tid = threadIdx.x;
  const size_t base = (size_t)row * D_IN;
  __shared__ float red[4];
  __shared__ float s_mu, s_var;
  float y0 = X[base + tid] + Z[base + tid];
  float y1 = X[base + tid + 256] + Z[base + tid + 256];
  float s = y0 + y1;
  for (int o = 32; o; o >>= 1) s += __shfl_xor(s, o);
  if ((tid & 63) == 0) red[tid >> 6] = s;
  __syncthreads();
  if (tid == 0) s_mu = (red[0] + red[1] + red[2] + red[3]) * (1.f / D_IN);
  __syncthreads();
  const float mu = s_mu;
  float d0 = y0 - mu, d1 = y1 - mu;
  float v = d0 * d0 + d1 * d1;
  for (int o = 32; o; o >>= 1) v += __shfl_xor(v, o);
  if ((tid & 63) == 0) red[tid >> 6] = v;
  __syncthreads();
  if (tid == 0) s_var = (red[0] + red[1] + red[2] + red[3]) * (1.f / D_IN);
  __syncthreads();
  const float rs = rsqrtf(s_var + LN_EPS);
  Z[base + tid]       = d0 * rs * gamma[tid]       + beta[tid];
  Z[base + tid + 256] = d1 * rs * gamma[tid + 256] + beta[tid + 256];
}

// ---------------------------------------------------------------------------
extern "C" void kernel_launch(void* const* d_in, const int* in_sizes, int n_in,
                              void* d_out, int out_size, void* d_ws, size_t ws_size,
                              hipStream_t stream)
{
  const float* X     = (const float*)d_in[0];
  const float* W1    = (const float*)d_in[1];
  const float* W2    = (const float*)d_in[2];
  const float* W3    = (const float*)d_in[3];
  const float* U1    = (const float*)d_in[4];
  const float* U2    = (const float*)d_in[5];
  const float* U3    = (const float*)d_in[6];
  const float* gamma = (const float*)d_in[7];
  const float* beta  = (const float*)d_in[8];

  char* w = (char*)d_ws;
  float* S    = (float*)w;            w += (size_t)N_TOK * N_TOK * 4;   // 64 MB
  u16* Xbf    = (u16*)w;              w += (size_t)N_TOK * D_IN * 2;
  u16* Xa0    = (u16*)w;              w += (size_t)N_TOK * D_IN * 2;
  u16* Xa1    = (u16*)w;              w += (size_t)N_TOK * D_IN * 2;
  u16* XaT0   = (u16*)w;              w += (size_t)D_IN * N_TOK * 2;
  u16* XaT1   = (u16*)w;              w += (size_t)D_IN * N_TOK * 2;
  u16* hb     = (u16*)w;              w += (size_t)N_TOK * D_ATTN * 2;
  u16* qb     = (u16*)w;              w += (size_t)N_TOK * D_ATTN * 2;
  u16* kb     = (u16*)w;              w += (size_t)N_TOK * D_ATTN * 2;
  u16* W1b    = (u16*)w;              w += (size_t)D_ATTN * D_IN * 2;
  u16* W2b    = (u16*)w;              w += (size_t)D_ATTN * D_ATTN * 2;
  u16* W3b    = (u16*)w;              w += (size_t)D_ATTN * D_IN * 2;
  u16* U1b    = (u16*)w;              w += (size_t)2 * D_IN * D_IN * 2;
  u16* U2b    = (u16*)w;              w += (size_t)2 * D_IN * D_IN * 2;
  u16* U3b    = (u16*)w;              w += (size_t)2 * D_IN * D_IN * 2;

  float* Z = (float*)d_out;

  hipMemsetAsync(d_out, 0, (size_t)N_TOK * D_IN * 4, stream);

  const int nXD4 = N_TOK * D_IN / 4;
  cvt_bf4<<<(nXD4 + 255) / 256, 256, 0, stream>>>(X, Xbf, Xa0, nXD4);
  cvt_bf4<<<(D_ATTN * D_IN / 4 + 255) / 256, 256, 0, stream>>>(W1, W1b, nullptr, D_ATTN * D_IN / 4);
  cvt_bf4<<<(D_ATTN * D_ATTN / 4 + 255) / 256, 256, 0, stream>>>(W2, W2b, nullptr, D_ATTN * D_ATTN / 4);
  cvt_bf4<<<(D_ATTN * D_IN / 4 + 255) / 256, 256, 0, stream>>>(W3, W3b, nullptr, D_ATTN * D_IN / 4);
  const int nU4 = 2 * D_IN * D_IN / 4;
  cvt_bf4<<<(nU4 + 255) / 256, 256, 0, stream>>>(U1, U1b, nullptr, nU4);
  cvt_bf4<<<(nU4 + 255) / 256, 256, 0, stream>>>(U2, U2b, nullptr, nU4);
  cvt_bf4<<<(nU4 + 255) / 256, 256, 0, stream>>>(U3, U3b, nullptr, nU4);
  tpose_bf<<<dim3(D_IN / 32, N_TOK / 32), 256, 0, stream>>>(X, XaT0);

  u16* XaC[2]  = {Xa0, Xa1};
  u16* XaTC[2] = {XaT0, XaT1};

  for (int n = 0; n < 2; ++n) {
    const int cur = n & 1, nxt = cur ^ 1;
    const size_t uoff = (size_t)n * D_IN * D_IN;
    // h = tanh(Xa @ W1^T)  [4096,64]
    gemm128<1, 1, D_IN><<<dim3(1, 32), 256, 0, stream>>>(
        XaC[cur], D_IN, 0, W1b, D_IN,
        nullptr, 0, 0, nullptr, 0, nullptr, 0, 0, nullptr, 0,
        nullptr, hb, nullptr, D_ATTN, 0);
    // k = Xa @ W3^T
    gemm128<2, 1, D_IN><<<dim3(1, 32), 256, 0, stream>>>(
        XaC[cur], D_IN, 0, W3b, D_IN,
        nullptr, 0, 0, nullptr, 0, nullptr, 0, 0, nullptr, 0,
        nullptr, kb, nullptr, D_ATTN, 0);
    // q = h @ W2^T
    gemm128<2, 1, D_ATTN><<<dim3(1, 32), 256, 0, stream>>>(
        hb, D_ATTN, 0, W2b, D_ATTN,
        nullptr, 0, 0, nullptr, 0, nullptr, 0, 0, nullptr, 0,
        nullptr, qb, nullptr, D_ATTN, 0);
    // S = q @ k^T
    gemm128<0, 1, D_ATTN><<<dim3(64, 32), 256, 0, stream>>>(
        qb, D_ATTN, 0, kb, D_ATTN,
        nullptr, 0, 0, nullptr, 0, nullptr, 0, 0, nullptr, 0,
        S, nullptr, nullptr, N_TOK, 0);
    // softmax + top-p -> A (bf16, in-place over S; one row per wave)
    nucleus_wave<<<N_TOK / 4, 256, 0, stream>>>(S);
    // Xa_new = A @ Xa : A lda=8192, B = XaT cur; dual-write Xa_new, XaT_new
    gemm128<4, 1, N_TOK><<<dim3(8, 32), 256, 0, stream>>>(
        (const u16*)S, 2 * N_TOK, 0, XaTC[cur], N_TOK,
        nullptr, 0, 0, nullptr, 0, nullptr, 0, 0, nullptr, 0,
        nullptr, XaC[nxt], XaTC[nxt], D_IN, N_TOK);
    // Z += Xf@U1^T + Xb@U2^T + Xa_new@U3^T   (fused 3-segment)
    gemm128<3, 3, D_IN><<<dim3(8, 32), 256, 0, stream>>>(
        Xbf, D_IN, -(n + 1), U1b + uoff, D_IN,
        Xbf, D_IN,  (n + 1), U2b + uoff, D_IN,
        XaC[nxt], D_IN, 0,   U3b + uoff, D_IN,
        Z, nullptr, nullptr, D_IN, 0);
  }

  // y = X + Z ; LayerNorm (in place over Z = d_out)
  ln_kernel<<<N_TOK, 256, 0, stream>>>(X, Z, gamma, beta);
}